// Round 15
// baseline (155.836 us; speedup 1.0000x reference)
//
#include <hip/hip_runtime.h>
#include <hip/hip_bf16.h>
#include <math.h>

#define F_IN 128
#define H_DIM 256
#define C_OUT 40

typedef __attribute__((ext_vector_type(8))) short short8v;
typedef __attribute__((ext_vector_type(4))) float float4v;

__device__ __forceinline__ unsigned short f2bf(float f) {
    union { float f; unsigned int u; } c; c.f = f;
    unsigned int r = (c.u + 0x7fffu + ((c.u >> 16) & 1u)) >> 16;  // RNE
    return (unsigned short)r;
}
__device__ __forceinline__ float bf2f(unsigned short u) {
    union { unsigned int u; float f; } c; c.u = ((unsigned int)u) << 16;
    return c.f;
}

// ---------------------------------------------------------------------------
// prep: [blocks 0..nA)        convert x -> x_b (bf16), 8 elems/thread
//       [blocks nA..nA+128)   W1 -> W1T bf16 (coalesced 256B writes)
// block nA thread 0 also zeroes the bn completion counter (stream-ordered,
// re-zeroed every call -> deterministic under graph replay).
// (head zeroed by hipMemsetAsync)
// ---------------------------------------------------------------------------
__global__ __launch_bounds__(256) void prep(const float* __restrict__ x,
                                            const float* __restrict__ W1,
                                            unsigned short* __restrict__ x_b,
                                            unsigned short* __restrict__ w1t,
                                            int* __restrict__ bn_counter,
                                            int N, int nA) {
    int b = blockIdx.x;
    if (b < nA) {
        long long i = ((long long)b * 256 + threadIdx.x) * 8;
        if (i + 7 < (long long)N * F_IN) {
            float4 v0 = *reinterpret_cast<const float4*>(x + i);
            float4 v1 = *reinterpret_cast<const float4*>(x + i + 4);
            short8v o;
            o[0] = (short)f2bf(v0.x); o[1] = (short)f2bf(v0.y);
            o[2] = (short)f2bf(v0.z); o[3] = (short)f2bf(v0.w);
            o[4] = (short)f2bf(v1.x); o[5] = (short)f2bf(v1.y);
            o[6] = (short)f2bf(v1.z); o[7] = (short)f2bf(v1.w);
            *reinterpret_cast<short8v*>(x_b + i) = o;
        }
    } else {
        if (b == nA && threadIdx.x == 0) *bn_counter = 0;
        int t = (b - nA) * 2 + (threadIdx.x >> 7);   // output row of W1T (= col of W1)
        int k = threadIdx.x & 127;                    // input row of W1
        w1t[t * F_IN + k] = f2bf(W1[(size_t)k * H_DIM + t]);
    }
}

// ---------------------------------------------------------------------------
// build per-dst linked-list adjacency in ONE pass.
// head stores edge_index+1 (0 = empty; head pre-zeroed by memset).
// ---------------------------------------------------------------------------
__global__ __launch_bounds__(256) void build_list(const int* __restrict__ src,
                                                  const int* __restrict__ dst,
                                                  int* __restrict__ head,
                                                  int2* __restrict__ listbuf, int E) {
    int i = blockIdx.x * 256 + threadIdx.x;
    if (i >= E) return;
    int d = dst[i];
    int prev = atomicExch(&head[d], i + 1);
    listbuf[i] = make_int2(src[i], prev);
}

// ---------------------------------------------------------------------------
// gather-aggregate, 8 independent chains per wave (8 lanes/node, 32B/lane)
// agg_b[d,:] = bf16( (1+eps)*x[d,:] + sum x[s,:] )     [round-10 proven config]
// ---------------------------------------------------------------------------
__global__ __launch_bounds__(256) void gather_agg(const unsigned short* __restrict__ xb,
                                                  const float* __restrict__ epsp,
                                                  const int* __restrict__ head,
                                                  const int2* __restrict__ listbuf,
                                                  unsigned short* __restrict__ aggb, int N) {
    int wave = (blockIdx.x * 256 + (int)threadIdx.x) >> 6;
    int lane = threadIdx.x & 63;
    int g = lane >> 3;            // chain 0..7 within wave
    int lr = lane & 7;            // lane within chain: 8 x 32B = 256B row
    int node = wave * 8 + g;
    bool valid = node < N;
    int j = valid ? head[node] : 0;

    float acc[16] = {};
    while (__any(j > 0)) {
        if (j > 0) {
            int2 e = listbuf[j - 1];
            const unsigned short* rp = xb + (size_t)e.x * F_IN + lr * 16;
            short8v v0 = *reinterpret_cast<const short8v*>(rp);
            short8v v1 = *reinterpret_cast<const short8v*>(rp + 8);
            j = e.y;
            #pragma unroll
            for (int t = 0; t < 8; ++t) acc[t] += bf2f((unsigned short)v0[t]);
            #pragma unroll
            for (int t = 0; t < 8; ++t) acc[8 + t] += bf2f((unsigned short)v1[t]);
        }
    }

    if (valid) {
        float sc = 1.0f + epsp[0];
        const unsigned short* xp = xb + (size_t)node * F_IN + lr * 16;
        short8v x0 = *reinterpret_cast<const short8v*>(xp);
        short8v x1 = *reinterpret_cast<const short8v*>(xp + 8);
        short8v o0, o1;
        #pragma unroll
        for (int t = 0; t < 8; ++t) {
            o0[t] = (short)f2bf(fmaf(sc, bf2f((unsigned short)x0[t]), acc[t]));
            o1[t] = (short)f2bf(fmaf(sc, bf2f((unsigned short)x1[t]), acc[8 + t]));
        }
        unsigned short* op = aggb + (size_t)node * F_IN + lr * 16;
        *reinterpret_cast<short8v*>(op) = o0;
        *reinterpret_cast<short8v*>(op + 8) = o1;
    }
}

// ---------------------------------------------------------------------------
// gemm1 MFMA bf16, tile 128x128 (grid y=2) + BN-stat partials.
// h1[row][col] = bf16(relu(agg[row,:] @ W1[:,col] + b1[col]))   ROW-MAJOR out
// partials[bx*512 + n0+col] = sum ; partials[bx*512 + 256 + n0+col] = sumsq
// ---------------------------------------------------------------------------
__global__ __launch_bounds__(256) void gemm1_mfma(const unsigned short* __restrict__ agg_b,
                                                  const unsigned short* __restrict__ w1t,
                                                  const float* __restrict__ b1,
                                                  unsigned short* __restrict__ h1,
                                                  float* __restrict__ partials, int N) {
    __shared__ short As[128][136];   // A tile, padded; reused as T[128][136]
    __shared__ short Bs[128][136];   // W1T tile (row = output col)
    __shared__ float sums_l[128], ssq_l[128];

    int tid = threadIdx.x;
    int m0 = blockIdx.x * 128;
    int n0 = blockIdx.y * 128;

    if (tid < 128) { sums_l[tid] = 0.f; ssq_l[tid] = 0.f; }

    #pragma unroll
    for (int i = 0; i < 8; ++i) {
        int c = tid + i * 256;          // 0..2047
        int row = c >> 4, ck = c & 15;
        int gr = m0 + row;
        short8v v = {0, 0, 0, 0, 0, 0, 0, 0};
        if (gr < N) v = *reinterpret_cast<const short8v*>(agg_b + (size_t)gr * F_IN + ck * 8);
        *reinterpret_cast<short8v*>(&As[row][ck * 8]) = v;
    }
    #pragma unroll
    for (int i = 0; i < 8; ++i) {
        int c = tid + i * 256;          // 0..2047
        int row = c >> 4, ck = c & 15;
        *reinterpret_cast<short8v*>(&Bs[row][ck * 8]) =
            *reinterpret_cast<const short8v*>(w1t + (size_t)(n0 + row) * F_IN + ck * 8);
    }
    __syncthreads();

    int w = tid >> 6, lane = tid & 63;
    int wm = w >> 1, wn = w & 1;
    int lr = lane & 15, lk = (lane >> 4) * 8;

    float4v acc[4][4] = {};
    #pragma unroll
    for (int ks = 0; ks < 4; ++ks) {
        int k0 = ks * 32 + lk;
        short8v a[4], b[4];
        #pragma unroll
        for (int am = 0; am < 4; ++am)
            a[am] = *reinterpret_cast<short8v*>(&As[wm * 64 + am * 16 + lr][k0]);
        #pragma unroll
        for (int bn = 0; bn < 4; ++bn)
            b[bn] = *reinterpret_cast<short8v*>(&Bs[wn * 64 + bn * 16 + lr][k0]);
        #pragma unroll
        for (int am = 0; am < 4; ++am)
            #pragma unroll
            for (int bn = 0; bn < 4; ++bn)
                acc[am][bn] = __builtin_amdgcn_mfma_f32_16x16x32_bf16(a[am], b[bn], acc[am][bn], 0, 0, 0);
    }

    __syncthreads();  // done reading As; reuse as row-major staging T[128][136]
    short (*T)[136] = As;
    #pragma unroll
    for (int bn = 0; bn < 4; ++bn) {
        int col = wn * 64 + bn * 16 + lr;   // local col 0..127
        float bias = b1[n0 + col];
        float ps = 0.f, pss = 0.f;
        #pragma unroll
        for (int am = 0; am < 4; ++am) {
            #pragma unroll
            for (int r = 0; r < 4; ++r) {
                int rowl = wm * 64 + am * 16 + (lane >> 4) * 4 + r;
                float v = fmaxf(acc[am][bn][r] + bias, 0.f);
                unsigned short ub = f2bf(v);
                T[rowl][col] = (short)ub;
                if (m0 + rowl < N) {
                    float vr = bf2f(ub);
                    ps += vr;
                    pss = fmaf(vr, vr, pss);
                }
            }
        }
        atomicAdd(&sums_l[col], ps);
        atomicAdd(&ssq_l[col], pss);
    }
    __syncthreads();

    #pragma unroll
    for (int i = 0; i < 8; ++i) {
        int c = tid + i * 256;          // 0..2047 : 128 rows x 16 chunks (128 cols)
        int row = c >> 4, ck = c & 15;
        int gr = m0 + row;
        if (gr < N)
            *reinterpret_cast<short8v*>(h1 + (size_t)gr * H_DIM + n0 + ck * 8) =
                *reinterpret_cast<short8v*>(&T[row][ck * 8]);
    }
    if (tid < 128) {
        size_t base = (size_t)blockIdx.x * 512;
        partials[base + n0 + tid] = sums_l[tid];
        partials[base + 256 + n0 + tid] = ssq_l[tid];
    }
}

// ---------------------------------------------------------------------------
// FUSED bn_reduce + bn_fold. 256 blocks: block k reduces partials for column k
// and publishes sums/sumsq with AGENT-scope stores; the LAST block to finish
// (device-scope counter) re-reads all 512 stats with AGENT-scope loads
// (cross-XCD safe) and performs the W2/b2 fold.
// ---------------------------------------------------------------------------
__global__ __launch_bounds__(256) void bn_reduce_fold(const float* __restrict__ partials,
                                                      int nbx,
                                                      float* __restrict__ sums,
                                                      float* __restrict__ sumsq,
                                                      int* __restrict__ counter,
                                                      const float* __restrict__ gamma,
                                                      const float* __restrict__ beta,
                                                      const float* __restrict__ W2,
                                                      const float* __restrict__ b2,
                                                      unsigned short* __restrict__ w2frag,
                                                      float* __restrict__ b2f, int N) {
    __shared__ float red[8];
    __shared__ int s_last;
    __shared__ float scale_s[H_DIM], shift_s[H_DIM];
    int k = blockIdx.x;
    float s = 0.f, ss = 0.f;
    for (int b = threadIdx.x; b < nbx; b += 256) {
        s += partials[(size_t)b * 512 + k];
        ss += partials[(size_t)b * 512 + 256 + k];
    }
    #pragma unroll
    for (int off = 32; off > 0; off >>= 1) {
        s += __shfl_down(s, off, 64);
        ss += __shfl_down(ss, off, 64);
    }
    int wave = threadIdx.x >> 6;
    int lane = threadIdx.x & 63;
    if (lane == 0) { red[wave] = s; red[4 + wave] = ss; }
    __syncthreads();
    if (threadIdx.x == 0) {
        float st = red[0] + red[1] + red[2] + red[3];
        float sst = red[4] + red[5] + red[6] + red[7];
        __hip_atomic_store(&sums[k], st, __ATOMIC_RELAXED, __HIP_MEMORY_SCOPE_AGENT);
        __hip_atomic_store(&sumsq[k], sst, __ATOMIC_RELAXED, __HIP_MEMORY_SCOPE_AGENT);
        __threadfence();
        int old = atomicAdd(counter, 1);
        s_last = (old == (int)gridDim.x - 1) ? 1 : 0;
    }
    __syncthreads();
    if (!s_last) return;

    // last block: fold. Read all stats device-coherently.
    int t = threadIdx.x;
    float sv = __hip_atomic_load(&sums[t], __ATOMIC_RELAXED, __HIP_MEMORY_SCOPE_AGENT);
    float ssv = __hip_atomic_load(&sumsq[t], __ATOMIC_RELAXED, __HIP_MEMORY_SCOPE_AGENT);
    float invN = 1.0f / (float)N;
    float mean = sv * invN;
    float var = ssv * invN - mean * mean;
    float scale = gamma[t] * rsqrtf(var + 1e-5f);
    float shift = beta[t] - mean * scale;
    scale_s[t] = scale;
    shift_s[t] = shift;
    __syncthreads();
    if (t < 48) {
        if (t < C_OUT) {
            float acc = b2[t];
            for (int j = 0; j < H_DIM; ++j) acc = fmaf(shift_s[j], W2[j * C_OUT + t], acc);
            b2f[t] = acc;
        } else {
            b2f[t] = -1e30f;
        }
    }
    for (int u = t; u < 1536; u += 256) {
        int lane2 = u & 63, tt = u >> 6;
        int ks = tt / 3, bf = tt - ks * 3;
        int col = bf * 16 + (lane2 & 15);
        int kb = ks * 32 + (lane2 >> 4) * 8;
        short8v o;
        #pragma unroll
        for (int e = 0; e < 8; ++e) {
            int kk = kb + e;
            float v = (col < C_OUT) ? scale_s[kk] * W2[kk * C_OUT + col] : 0.f;
            o[e] = (short)f2bf(v);
        }
        *reinterpret_cast<short8v*>(w2frag + (size_t)u * 8) = o;
    }
}

// ---------------------------------------------------------------------------
// gemm2 + log_softmax via MFMA. Block = 4 waves; wave = 16 rows x 48 cols
// (padded from 40), K=256 in 8 MFMA steps. No LDS, no atomics.
// ---------------------------------------------------------------------------
__global__ __launch_bounds__(256) void gemm2_lsm(const unsigned short* __restrict__ h1,
                                                 const unsigned short* __restrict__ w2frag,
                                                 const float* __restrict__ b2f,
                                                 float* __restrict__ out, int N) {
    int tid = threadIdx.x;
    int wm = tid >> 6;
    int lane = tid & 63;
    int lr = lane & 15;
    int g = lane >> 4;                 // 0..3
    int row0 = blockIdx.x * 64 + wm * 16;
    int arow = row0 + lr;
    if (arow >= N) arow = N - 1;

    // A: full K=256 row in registers (8 x 16B contiguous chunks)
    short8v a[8];
    const unsigned short* ap = h1 + (size_t)arow * H_DIM + g * 8;
    #pragma unroll
    for (int ks = 0; ks < 8; ++ks)
        a[ks] = *reinterpret_cast<const short8v*>(ap + ks * 32);

    float4v acc[3] = {};
    #pragma unroll
    for (int ks = 0; ks < 8; ++ks) {
        #pragma unroll
        for (int bf = 0; bf < 3; ++bf) {
            short8v b = *reinterpret_cast<const short8v*>(
                w2frag + (size_t)(((ks * 3 + bf) << 6) + lane) * 8);
            acc[bf] = __builtin_amdgcn_mfma_f32_16x16x32_bf16(a[ks], b, acc[bf], 0, 0, 0);
        }
    }

    // epilogue: logits row = row0 + g*4 + r, col = bf*16 + (lane&15)
    float b0 = b2f[lr], b1v = b2f[16 + lr], b2v = b2f[32 + lr];  // pads = -1e30
    #pragma unroll
    for (int r = 0; r < 4; ++r) {
        float v0 = acc[0][r] + b0;
        float v1 = acc[1][r] + b1v;
        float v2 = acc[2][r] + b2v;
        float m = fmaxf(fmaxf(v0, v1), v2);
        #pragma unroll
        for (int o = 1; o < 16; o <<= 1) m = fmaxf(m, __shfl_xor(m, o, 64));
        float s = __expf(v0 - m) + __expf(v1 - m) + __expf(v2 - m);
        #pragma unroll
        for (int o = 1; o < 16; o <<= 1) s += __shfl_xor(s, o, 64);
        float lse = m + __logf(s);
        int row = row0 + g * 4 + r;
        if (row < N) {
            float* op = out + (size_t)row * C_OUT;
            op[lr] = v0 - lse;
            op[16 + lr] = v1 - lse;
            if (lr < 8) op[32 + lr] = v2 - lse;
        }
    }
}

// ---------------------------------------------------------------------------
extern "C" void kernel_launch(void* const* d_in, const int* in_sizes, int n_in,
                              void* d_out, int out_size, void* d_ws, size_t ws_size,
                              hipStream_t stream) {
    const float* x     = (const float*)d_in[0];
    const int*   ei    = (const int*)d_in[1];
    const float* eps   = (const float*)d_in[2];
    const float* W1    = (const float*)d_in[3];
    const float* b1    = (const float*)d_in[4];
    const float* gamma = (const float*)d_in[5];
    const float* beta  = (const float*)d_in[6];
    const float* W2    = (const float*)d_in[7];
    const float* b2    = (const float*)d_in[8];
    float* out = (float*)d_out;

    int N = in_sizes[0] / F_IN;   // 50000
    int E = in_sizes[1] / 2;      // 800000
    const int* srcIdx = ei;
    const int* dstIdx = ei + E;

    int nbx = (N + 127) / 128;    // gemm1 row-blocks (391)

    // workspace layout
    unsigned short* x_b    = (unsigned short*)d_ws;                 // N*128
    unsigned short* agg_b  = x_b + (size_t)N * F_IN;                // N*128
    unsigned short* w1t    = agg_b + (size_t)N * F_IN;              // 256*128
    unsigned short* h1     = w1t + H_DIM * F_IN;                    // N*256 row-major
    float* partials = (float*)(h1 + (size_t)N * H_DIM);             // nbx*512
    float* sums   = partials + (size_t)nbx * 512;                   // 256
    float* sumsq  = sums + H_DIM;                                   // 256
    int*   bn_ctr = (int*)(sumsq + H_DIM);                          // 1 (+pad to 8)
    unsigned short* w2frag = (unsigned short*)(bn_ctr + 8);         // 1536*8
    float* b2f    = (float*)(w2frag + 1536 * 8);                    // 48

    // adjacency scratch aliased into h1 region (dead before gemm1 writes h1)
    int*  head    = (int*)h1;            // N
    int2* listbuf = (int2*)(head + N);   // E (8B each)

    // head = 0 (empty) via DMA memset; graph-capturable
    hipMemsetAsync(head, 0, (size_t)N * sizeof(int), stream);

    int nA = (N * 16 + 255) / 256;
    hipLaunchKernelGGL(prep, dim3(nA + 128), dim3(256), 0, stream,
                       x, W1, x_b, w1t, bn_ctr, N, nA);

    hipLaunchKernelGGL(build_list, dim3((E + 255) / 256), dim3(256), 0, stream,
                       srcIdx, dstIdx, head, listbuf, E);

    // 8 nodes per wave, 4 waves per block -> 32 nodes per block
    hipLaunchKernelGGL(gather_agg, dim3((N + 31) / 32), dim3(256), 0, stream,
                       x_b, eps, head, listbuf, agg_b, N);

    dim3 g1(nbx, 2);
    hipLaunchKernelGGL(gemm1_mfma, g1, dim3(256), 0, stream,
                       agg_b, w1t, b1, h1, partials, N);

    hipLaunchKernelGGL(bn_reduce_fold, dim3(H_DIM), dim3(256), 0, stream,
                       partials, nbx, sums, sumsq, bn_ctr,
                       gamma, beta, W2, b2, w2frag, b2f, N);

    hipLaunchKernelGGL(gemm2_lsm, dim3((N + 63) / 64), dim3(256), 0, stream,
                       h1, w2frag, b2f, out, N);
}

// Round 16
// 147.850 us; speedup vs baseline: 1.0540x; 1.0540x over previous
//
#include <hip/hip_runtime.h>
#include <hip/hip_bf16.h>
#include <math.h>

#define F_IN 128
#define H_DIM 256
#define C_OUT 40

typedef __attribute__((ext_vector_type(8))) short short8v;
typedef __attribute__((ext_vector_type(4))) float float4v;

__device__ __forceinline__ unsigned short f2bf(float f) {
    union { float f; unsigned int u; } c; c.f = f;
    unsigned int r = (c.u + 0x7fffu + ((c.u >> 16) & 1u)) >> 16;  // RNE
    return (unsigned short)r;
}
__device__ __forceinline__ float bf2f(unsigned short u) {
    union { unsigned int u; float f; } c; c.u = ((unsigned int)u) << 16;
    return c.f;
}

// ---------------------------------------------------------------------------
// prep: [blocks 0..nA)        convert x -> x_b (bf16), 8 elems/thread
//       [blocks nA..nA+128)   W1 -> W1T bf16 (coalesced 256B writes)
//       [blocks nA+128..)     head = -1
// ---------------------------------------------------------------------------
__global__ __launch_bounds__(256) void prep(const float* __restrict__ x,
                                            const float* __restrict__ W1,
                                            unsigned short* __restrict__ x_b,
                                            unsigned short* __restrict__ w1t,
                                            int* __restrict__ head,
                                            int N, int nA) {
    int b = blockIdx.x;
    if (b < nA) {
        long long i = ((long long)b * 256 + threadIdx.x) * 8;
        if (i + 7 < (long long)N * F_IN) {
            float4 v0 = *reinterpret_cast<const float4*>(x + i);
            float4 v1 = *reinterpret_cast<const float4*>(x + i + 4);
            short8v o;
            o[0] = (short)f2bf(v0.x); o[1] = (short)f2bf(v0.y);
            o[2] = (short)f2bf(v0.z); o[3] = (short)f2bf(v0.w);
            o[4] = (short)f2bf(v1.x); o[5] = (short)f2bf(v1.y);
            o[6] = (short)f2bf(v1.z); o[7] = (short)f2bf(v1.w);
            *reinterpret_cast<short8v*>(x_b + i) = o;
        }
    } else if (b < nA + 128) {
        int t = (b - nA) * 2 + (threadIdx.x >> 7);   // output row of W1T (= col of W1)
        int k = threadIdx.x & 127;                    // input row of W1
        w1t[t * F_IN + k] = f2bf(W1[(size_t)k * H_DIM + t]);
    } else {
        int i = (b - nA - 128) * 256 + threadIdx.x;
        if (i < N) head[i] = -1;
    }
}

// ---------------------------------------------------------------------------
// build per-dst linked-list adjacency in ONE pass.
// listbuf[i] = {src[i], prev_head}; writes coalesced by edge index.
// ---------------------------------------------------------------------------
__global__ __launch_bounds__(256) void build_list(const int* __restrict__ src,
                                                  const int* __restrict__ dst,
                                                  int* __restrict__ head,
                                                  int2* __restrict__ listbuf, int E) {
    int i = blockIdx.x * 256 + threadIdx.x;
    if (i >= E) return;
    int d = dst[i];
    int prev = atomicExch(&head[d], i);
    listbuf[i] = make_int2(src[i], prev);
}

// ---------------------------------------------------------------------------
// gather-aggregate, 8 independent chains per wave (8 lanes/node, 32B/lane)
// agg_b[d,:] = bf16( (1+eps)*x[d,:] + sum x[s,:] )     [round-10 proven config]
// ---------------------------------------------------------------------------
__global__ __launch_bounds__(256) void gather_agg(const unsigned short* __restrict__ xb,
                                                  const float* __restrict__ epsp,
                                                  const int* __restrict__ head,
                                                  const int2* __restrict__ listbuf,
                                                  unsigned short* __restrict__ aggb, int N) {
    int wave = (blockIdx.x * 256 + (int)threadIdx.x) >> 6;
    int lane = threadIdx.x & 63;
    int g = lane >> 3;            // chain 0..7 within wave
    int lr = lane & 7;            // lane within chain: 8 x 32B = 256B row
    int node = wave * 8 + g;
    bool valid = node < N;
    int j = valid ? head[node] : -1;

    float acc[16] = {};
    while (__any(j >= 0)) {
        if (j >= 0) {
            int2 e = listbuf[j];
            const unsigned short* rp = xb + (size_t)e.x * F_IN + lr * 16;
            short8v v0 = *reinterpret_cast<const short8v*>(rp);
            short8v v1 = *reinterpret_cast<const short8v*>(rp + 8);
            j = e.y;
            #pragma unroll
            for (int t = 0; t < 8; ++t) acc[t] += bf2f((unsigned short)v0[t]);
            #pragma unroll
            for (int t = 0; t < 8; ++t) acc[8 + t] += bf2f((unsigned short)v1[t]);
        }
    }

    if (valid) {
        float sc = 1.0f + epsp[0];
        const unsigned short* xp = xb + (size_t)node * F_IN + lr * 16;
        short8v x0 = *reinterpret_cast<const short8v*>(xp);
        short8v x1 = *reinterpret_cast<const short8v*>(xp + 8);
        short8v o0, o1;
        #pragma unroll
        for (int t = 0; t < 8; ++t) {
            o0[t] = (short)f2bf(fmaf(sc, bf2f((unsigned short)x0[t]), acc[t]));
            o1[t] = (short)f2bf(fmaf(sc, bf2f((unsigned short)x1[t]), acc[8 + t]));
        }
        unsigned short* op = aggb + (size_t)node * F_IN + lr * 16;
        *reinterpret_cast<short8v*>(op) = o0;
        *reinterpret_cast<short8v*>(op + 8) = o1;
    }
}

// ---------------------------------------------------------------------------
// gemm1 MFMA bf16, tile 128x128 (grid y=2) + BN-stat partials.
// h1[row][col] = bf16(relu(agg[row,:] @ W1[:,col] + b1[col]))   ROW-MAJOR out
// partials[bx*512 + n0+col] = sum ; partials[bx*512 + 256 + n0+col] = sumsq
// ---------------------------------------------------------------------------
__global__ __launch_bounds__(256) void gemm1_mfma(const unsigned short* __restrict__ agg_b,
                                                  const unsigned short* __restrict__ w1t,
                                                  const float* __restrict__ b1,
                                                  unsigned short* __restrict__ h1,
                                                  float* __restrict__ partials, int N) {
    __shared__ short As[128][136];   // A tile, padded; reused as T[128][136]
    __shared__ short Bs[128][136];   // W1T tile (row = output col)
    __shared__ float sums_l[128], ssq_l[128];

    int tid = threadIdx.x;
    int m0 = blockIdx.x * 128;
    int n0 = blockIdx.y * 128;

    if (tid < 128) { sums_l[tid] = 0.f; ssq_l[tid] = 0.f; }

    #pragma unroll
    for (int i = 0; i < 8; ++i) {
        int c = tid + i * 256;          // 0..2047
        int row = c >> 4, ck = c & 15;
        int gr = m0 + row;
        short8v v = {0, 0, 0, 0, 0, 0, 0, 0};
        if (gr < N) v = *reinterpret_cast<const short8v*>(agg_b + (size_t)gr * F_IN + ck * 8);
        *reinterpret_cast<short8v*>(&As[row][ck * 8]) = v;
    }
    #pragma unroll
    for (int i = 0; i < 8; ++i) {
        int c = tid + i * 256;          // 0..2047
        int row = c >> 4, ck = c & 15;
        *reinterpret_cast<short8v*>(&Bs[row][ck * 8]) =
            *reinterpret_cast<const short8v*>(w1t + (size_t)(n0 + row) * F_IN + ck * 8);
    }
    __syncthreads();

    int w = tid >> 6, lane = tid & 63;
    int wm = w >> 1, wn = w & 1;
    int lr = lane & 15, lk = (lane >> 4) * 8;

    float4v acc[4][4] = {};
    #pragma unroll
    for (int ks = 0; ks < 4; ++ks) {
        int k0 = ks * 32 + lk;
        short8v a[4], b[4];
        #pragma unroll
        for (int am = 0; am < 4; ++am)
            a[am] = *reinterpret_cast<short8v*>(&As[wm * 64 + am * 16 + lr][k0]);
        #pragma unroll
        for (int bn = 0; bn < 4; ++bn)
            b[bn] = *reinterpret_cast<short8v*>(&Bs[wn * 64 + bn * 16 + lr][k0]);
        #pragma unroll
        for (int am = 0; am < 4; ++am)
            #pragma unroll
            for (int bn = 0; bn < 4; ++bn)
                acc[am][bn] = __builtin_amdgcn_mfma_f32_16x16x32_bf16(a[am], b[bn], acc[am][bn], 0, 0, 0);
    }

    __syncthreads();  // done reading As; reuse as row-major staging T[128][136]
    short (*T)[136] = As;
    #pragma unroll
    for (int bn = 0; bn < 4; ++bn) {
        int col = wn * 64 + bn * 16 + lr;   // local col 0..127
        float bias = b1[n0 + col];
        float ps = 0.f, pss = 0.f;
        #pragma unroll
        for (int am = 0; am < 4; ++am) {
            #pragma unroll
            for (int r = 0; r < 4; ++r) {
                int rowl = wm * 64 + am * 16 + (lane >> 4) * 4 + r;
                float v = fmaxf(acc[am][bn][r] + bias, 0.f);
                unsigned short ub = f2bf(v);
                T[rowl][col] = (short)ub;
                if (m0 + rowl < N) {
                    float vr = bf2f(ub);
                    ps += vr;
                    pss = fmaf(vr, vr, pss);
                }
            }
        }
        atomicAdd(&sums_l[col], ps);
        atomicAdd(&ssq_l[col], pss);
    }
    __syncthreads();

    #pragma unroll
    for (int i = 0; i < 8; ++i) {
        int c = tid + i * 256;          // 0..2047 : 128 rows x 16 chunks (128 cols)
        int row = c >> 4, ck = c & 15;
        int gr = m0 + row;
        if (gr < N)
            *reinterpret_cast<short8v*>(h1 + (size_t)gr * H_DIM + n0 + ck * 8) =
                *reinterpret_cast<short8v*>(&T[row][ck * 8]);
    }
    if (tid < 128) {
        size_t base = (size_t)blockIdx.x * 512;
        partials[base + n0 + tid] = sums_l[tid];
        partials[base + 256 + n0 + tid] = ssq_l[tid];
    }
}

// ---------------------------------------------------------------------------
// parallel partials reduction: one block per BN column (256 blocks).
// ---------------------------------------------------------------------------
__global__ __launch_bounds__(256) void bn_reduce(const float* __restrict__ partials,
                                                 int nbx,
                                                 float* __restrict__ sums,
                                                 float* __restrict__ sumsq) {
    __shared__ float red[8];
    int k = blockIdx.x;
    float s = 0.f, ss = 0.f;
    for (int b = threadIdx.x; b < nbx; b += 256) {
        s += partials[(size_t)b * 512 + k];
        ss += partials[(size_t)b * 512 + 256 + k];
    }
    #pragma unroll
    for (int off = 32; off > 0; off >>= 1) {
        s += __shfl_down(s, off, 64);
        ss += __shfl_down(ss, off, 64);
    }
    int wave = threadIdx.x >> 6;
    int lane = threadIdx.x & 63;
    if (lane == 0) { red[wave] = s; red[4 + wave] = ss; }
    __syncthreads();
    if (threadIdx.x == 0) {
        sums[k] = red[0] + red[1] + red[2] + red[3];
        sumsq[k] = red[4] + red[5] + red[6] + red[7];
    }
}

// ---------------------------------------------------------------------------
// fold BN into W2/b2; emit W2f bf16 in MFMA FRAGMENT order
// (chunk u=(ks*3+bf)*64+lane: col=bf*16+(lane&15), k=ks*32+(lane>>4)*8+e).
// b2f padded to 48 with -1e30.
// ---------------------------------------------------------------------------
__global__ __launch_bounds__(256) void bn_fold(const float* __restrict__ sums,
                                               const float* __restrict__ sumsq,
                                               const float* __restrict__ gamma,
                                               const float* __restrict__ beta,
                                               const float* __restrict__ W2,
                                               const float* __restrict__ b2,
                                               unsigned short* __restrict__ w2frag,
                                               float* __restrict__ b2f, int N) {
    __shared__ float scale_s[H_DIM], shift_s[H_DIM];
    int k = threadIdx.x;
    float invN = 1.0f / (float)N;
    float mean = sums[k] * invN;
    float var = sumsq[k] * invN - mean * mean;
    float scale = gamma[k] * rsqrtf(var + 1e-5f);
    float shift = beta[k] - mean * scale;
    scale_s[k] = scale;
    shift_s[k] = shift;
    __syncthreads();
    if (k < 48) {
        if (k < C_OUT) {
            float acc = b2[k];
            for (int j = 0; j < H_DIM; ++j) acc = fmaf(shift_s[j], W2[j * C_OUT + k], acc);
            b2f[k] = acc;
        } else {
            b2f[k] = -1e30f;
        }
    }
    for (int u = threadIdx.x; u < 1536; u += 256) {
        int lane = u & 63, t = u >> 6;
        int ks = t / 3, bf = t - ks * 3;
        int col = bf * 16 + (lane & 15);
        int kb = ks * 32 + (lane >> 4) * 8;
        short8v o;
        #pragma unroll
        for (int e = 0; e < 8; ++e) {
            int kk = kb + e;
            float v = (col < C_OUT) ? scale_s[kk] * W2[kk * C_OUT + col] : 0.f;
            o[e] = (short)f2bf(v);
        }
        *reinterpret_cast<short8v*>(w2frag + (size_t)u * 8) = o;
    }
}

// ---------------------------------------------------------------------------
// gemm2 + log_softmax via MFMA. Block = 4 waves; wave = 16 rows x 48 cols
// (padded from 40), K=256 in 8 MFMA steps. No LDS, no atomics.
// ---------------------------------------------------------------------------
__global__ __launch_bounds__(256) void gemm2_lsm(const unsigned short* __restrict__ h1,
                                                 const unsigned short* __restrict__ w2frag,
                                                 const float* __restrict__ b2f,
                                                 float* __restrict__ out, int N) {
    int tid = threadIdx.x;
    int wm = tid >> 6;
    int lane = tid & 63;
    int lr = lane & 15;
    int g = lane >> 4;                 // 0..3
    int row0 = blockIdx.x * 64 + wm * 16;
    int arow = row0 + lr;
    if (arow >= N) arow = N - 1;

    // A: full K=256 row in registers (8 x 16B contiguous chunks)
    short8v a[8];
    const unsigned short* ap = h1 + (size_t)arow * H_DIM + g * 8;
    #pragma unroll
    for (int ks = 0; ks < 8; ++ks)
        a[ks] = *reinterpret_cast<const short8v*>(ap + ks * 32);

    float4v acc[3] = {};
    #pragma unroll
    for (int ks = 0; ks < 8; ++ks) {
        #pragma unroll
        for (int bf = 0; bf < 3; ++bf) {
            short8v b = *reinterpret_cast<const short8v*>(
                w2frag + (size_t)(((ks * 3 + bf) << 6) + lane) * 8);
            acc[bf] = __builtin_amdgcn_mfma_f32_16x16x32_bf16(a[ks], b, acc[bf], 0, 0, 0);
        }
    }

    // epilogue: logits row = row0 + g*4 + r, col = bf*16 + (lane&15)
    float b0 = b2f[lr], b1v = b2f[16 + lr], b2v = b2f[32 + lr];  // pads = -1e30
    #pragma unroll
    for (int r = 0; r < 4; ++r) {
        float v0 = acc[0][r] + b0;
        float v1 = acc[1][r] + b1v;
        float v2 = acc[2][r] + b2v;
        float m = fmaxf(fmaxf(v0, v1), v2);
        #pragma unroll
        for (int o = 1; o < 16; o <<= 1) m = fmaxf(m, __shfl_xor(m, o, 64));
        float s = __expf(v0 - m) + __expf(v1 - m) + __expf(v2 - m);
        #pragma unroll
        for (int o = 1; o < 16; o <<= 1) s += __shfl_xor(s, o, 64);
        float lse = m + __logf(s);
        int row = row0 + g * 4 + r;
        if (row < N) {
            float* op = out + (size_t)row * C_OUT;
            op[lr] = v0 - lse;
            op[16 + lr] = v1 - lse;
            if (lr < 8) op[32 + lr] = v2 - lse;
        }
    }
}

// ---------------------------------------------------------------------------
extern "C" void kernel_launch(void* const* d_in, const int* in_sizes, int n_in,
                              void* d_out, int out_size, void* d_ws, size_t ws_size,
                              hipStream_t stream) {
    const float* x     = (const float*)d_in[0];
    const int*   ei    = (const int*)d_in[1];
    const float* eps   = (const float*)d_in[2];
    const float* W1    = (const float*)d_in[3];
    const float* b1    = (const float*)d_in[4];
    const float* gamma = (const float*)d_in[5];
    const float* beta  = (const float*)d_in[6];
    const float* W2    = (const float*)d_in[7];
    const float* b2    = (const float*)d_in[8];
    float* out = (float*)d_out;

    int N = in_sizes[0] / F_IN;   // 50000
    int E = in_sizes[1] / 2;      // 800000
    const int* srcIdx = ei;
    const int* dstIdx = ei + E;

    int nbx = (N + 127) / 128;    // gemm1 row-blocks (391)

    // workspace layout
    unsigned short* x_b    = (unsigned short*)d_ws;                 // N*128
    unsigned short* agg_b  = x_b + (size_t)N * F_IN;                // N*128
    unsigned short* w1t    = agg_b + (size_t)N * F_IN;              // 256*128
    unsigned short* h1     = w1t + H_DIM * F_IN;                    // N*256 row-major
    float* partials = (float*)(h1 + (size_t)N * H_DIM);             // nbx*512
    float* sums   = partials + (size_t)nbx * 512;                   // 256
    float* sumsq  = sums + H_DIM;                                   // 256
    unsigned short* w2frag = (unsigned short*)(sumsq + H_DIM);      // 1536*8
    float* b2f    = (float*)(w2frag + 1536 * 8);                    // 48

    // adjacency scratch aliased into h1 region (dead before gemm1 writes h1)
    int*  head    = (int*)h1;            // N
    int2* listbuf = (int2*)(head + N);   // E (8B each)

    int nA = (N * 16 + 255) / 256;
    int nZ = (N + 255) / 256;
    hipLaunchKernelGGL(prep, dim3(nA + 128 + nZ), dim3(256), 0, stream,
                       x, W1, x_b, w1t, head, N, nA);

    hipLaunchKernelGGL(build_list, dim3((E + 255) / 256), dim3(256), 0, stream,
                       srcIdx, dstIdx, head, listbuf, E);

    // 8 nodes per wave, 4 waves per block -> 32 nodes per block
    hipLaunchKernelGGL(gather_agg, dim3((N + 31) / 32), dim3(256), 0, stream,
                       x_b, eps, head, listbuf, agg_b, N);

    dim3 g1(nbx, 2);
    hipLaunchKernelGGL(gemm1_mfma, g1, dim3(256), 0, stream,
                       agg_b, w1t, b1, h1, partials, N);

    hipLaunchKernelGGL(bn_reduce, dim3(H_DIM), dim3(256), 0, stream,
                       partials, nbx, sums, sumsq);

    hipLaunchKernelGGL(bn_fold, dim3(1), dim3(H_DIM), 0, stream,
                       sums, sumsq, gamma, beta, W2, b2, w2frag, b2f, N);

    hipLaunchKernelGGL(gemm2_lsm, dim3((N + 63) / 64), dim3(256), 0, stream,
                       h1, w2frag, b2f, out, N);
}